// Round 4
// baseline (155.671 us; speedup 1.0000x reference)
//
#include <hip/hip_runtime.h>

// NeighborlistBruteNsq: N=6144 atoms, all i<j pairs (P = N*(N-1)/2 = 18,871,296).
// Output [P,4] float32: [rx, ry, rz, d] if d <= 0.5 else zeros.
//
// Write-stream bound: 302 MB mandatory output (roofline ~44 us at fill-kernel
// BW). Strategy:
//  - Derive (i, j) analytically from np.triu_indices row-major order (never
//    read pair_i/pair_j: saves 151 MB of reads).
//  - Triangle row-folding: virtual row y combines real row y (len 6143-y)
//    with real row 6142-y (len y+1) -> exactly 6144 pairs. Zero wasted
//    threads (middle row 3071 covered twice with identical values -- benign).
//  - 2 pairs per thread (adjacent): 2x float4 = 32 B/lane, halves wave count.
//  - __builtin_nontemporal_store (on a native ext_vector_type -- HIP's float4
//    class is rejected by the builtin): streaming stores, no L2 allocate.
//  - PBC wrap via range reduction (positions in [0,10) so dx+5 in (-5,15)):
//    two predicated adds replace fmodf; bit-exact with np.remainder here.

#define N_ATOMS 6144
#define NROW    (N_ATOMS - 1)       /* 6143 real rows (i = 0..6142) */
#define BOX_LEN 10.0f
#define HALF_BOX 5.0f
#define CUTOFF_R 0.5f

typedef float f32x4 __attribute__((ext_vector_type(4)));

__device__ __forceinline__ float pbc_wrap(float dx) {
    // np.remainder(dx + 5, 10) - 5, valid for dx in (-10, 10)
    float x = dx + HALF_BOX;              // (-5, 15)
    x = (x >= BOX_LEN) ? x - BOX_LEN : x; // exact (same-exponent subtract)
    x = (x < 0.0f)     ? x + BOX_LEN : x; // matches np.remainder's fixup path
    return x - HALF_BOX;
}

__device__ __forceinline__ f32x4 pair_val(const float* __restrict__ pos,
                                          int i, int j) {
    const float rx = pbc_wrap(pos[3 * i + 0] - pos[3 * j + 0]);
    const float ry = pbc_wrap(pos[3 * i + 1] - pos[3 * j + 1]);
    const float rz = pbc_wrap(pos[3 * i + 2] - pos[3 * j + 2]);
    const float d  = sqrtf(rx * rx + ry * ry + rz * rz);
    f32x4 o = (f32x4){0.0f, 0.0f, 0.0f, 0.0f};
    if (d <= CUTOFF_R) o = (f32x4){rx, ry, rz, d};
    return o;
}

__global__ __launch_bounds__(256) void nbr_pairs_kernel(const float* __restrict__ pos,
                                                        float* __restrict__ out) {
    const int y = blockIdx.y;                                 // virtual row, 0..3071
    const int idx0 = (blockIdx.x * 256 + threadIdx.x) * 2;    // 0..6142 (step 2)

    const int lenA = NROW - y;                                // length of real row y
    const int iA = y, iB = NROW - 1 - y;

    f32x4 o[2];
    size_t gidx[2];
#pragma unroll
    for (int p = 0; p < 2; ++p) {
        const int idx = idx0 + p;
        int i, jrel;
        if (idx < lenA) { i = iA; jrel = idx; }
        else            { i = iB; jrel = idx - lenA; }
        const int j = i + 1 + jrel;
        const size_t base = (size_t)i * NROW - ((size_t)i * (i - 1)) / 2;
        gidx[p] = base + (size_t)jrel;
        o[p] = pair_val(pos, i, j);
    }

    f32x4* o4 = reinterpret_cast<f32x4*>(out);
    __builtin_nontemporal_store(o[0], &o4[gidx[0]]);
    __builtin_nontemporal_store(o[1], &o4[gidx[1]]);
}

extern "C" void kernel_launch(void* const* d_in, const int* in_sizes, int n_in,
                              void* d_out, int out_size, void* d_ws, size_t ws_size,
                              hipStream_t stream) {
    const float* positions = (const float*)d_in[0];
    float* out = (float*)d_out;

    // 3072 virtual rows x 6144 pairs, 2 pairs/thread -> 12 blocks of 256 per row.
    dim3 grid(N_ATOMS / 512, N_ATOMS / 2);
    nbr_pairs_kernel<<<grid, 256, 0, stream>>>(positions, out);
}

// Round 5
// 46.178 us; speedup vs baseline: 3.3711x; 3.3711x over previous
//
#include <hip/hip_runtime.h>

// NeighborlistBruteNsq: N=6144 atoms, all i<j pairs (P = N*(N-1)/2 = 18,871,296).
// Output [P,4] float32: [rx, ry, rz, d] if d <= 0.5 else zeros.
//
// Write-stream bound: 302 MB mandatory output (roofline ~44 us at fill-kernel
// BW, which sustains 85-90% of 8 TB/s with PLAIN stores). Strategy:
//  - Derive (i, j) analytically from np.triu_indices row-major order (never
//    read pair_i/pair_j: saves 151 MB of reads).
//  - Triangle row-folding: virtual row y combines real row y (len 6143-y)
//    with real row 6142-y (len y+1) -> exactly 6144 pairs. Zero wasted
//    threads (middle row 3071 covered twice with identical values -- benign).
//  - 2 pairs per thread, stride-256 within a 512-pair chunk: each store
//    instruction is 64 lanes x contiguous 16 B = fully coalesced 1 KB.
//    (R4 lesson: pairing ADJACENT pairs per thread makes each store 32B-
//    strided across lanes -> partial-line writes; with NT stores that
//    bypassed L2 write-combining and collapsed BW 3.4x. Plain stores only.)
//  - PBC wrap via range reduction (positions in [0,10) so dx+5 in (-5,15)):
//    two predicated adds replace fmodf; bit-exact with np.remainder here.

#define N_ATOMS 6144
#define NROW    (N_ATOMS - 1)       /* 6143 real rows (i = 0..6142) */
#define BOX_LEN 10.0f
#define HALF_BOX 5.0f
#define CUTOFF_R 0.5f

typedef float f32x4 __attribute__((ext_vector_type(4)));

__device__ __forceinline__ float pbc_wrap(float dx) {
    // np.remainder(dx + 5, 10) - 5, valid for dx in (-10, 10)
    float x = dx + HALF_BOX;              // (-5, 15)
    x = (x >= BOX_LEN) ? x - BOX_LEN : x; // exact (same-exponent subtract)
    x = (x < 0.0f)     ? x + BOX_LEN : x; // matches np.remainder's fixup path
    return x - HALF_BOX;
}

__device__ __forceinline__ f32x4 pair_val(const float* __restrict__ pos,
                                          int i, int j) {
    const float rx = pbc_wrap(pos[3 * i + 0] - pos[3 * j + 0]);
    const float ry = pbc_wrap(pos[3 * i + 1] - pos[3 * j + 1]);
    const float rz = pbc_wrap(pos[3 * i + 2] - pos[3 * j + 2]);
    const float d  = sqrtf(rx * rx + ry * ry + rz * rz);
    f32x4 o = (f32x4){0.0f, 0.0f, 0.0f, 0.0f};
    if (d <= CUTOFF_R) o = (f32x4){rx, ry, rz, d};
    return o;
}

__global__ __launch_bounds__(256) void nbr_pairs_kernel(const float* __restrict__ pos,
                                                        float* __restrict__ out) {
    const int y = blockIdx.y;                           // virtual row, 0..3071
    const int chunk0 = blockIdx.x * 512;                // 512-pair chunk base
    const int lane = threadIdx.x;

    const int lenA = NROW - y;                          // length of real row y
    const int iA = y, iB = NROW - 1 - y;

    f32x4* o4 = reinterpret_cast<f32x4*>(out);

#pragma unroll
    for (int p = 0; p < 2; ++p) {
        const int idx = chunk0 + p * 256 + lane;        // coalesced per store
        int i, jrel;
        if (idx < lenA) { i = iA; jrel = idx; }
        else            { i = iB; jrel = idx - lenA; }
        const int j = i + 1 + jrel;
        const size_t base = (size_t)i * NROW - ((size_t)i * (i - 1)) / 2;
        o4[base + (size_t)jrel] = pair_val(pos, i, j);
    }
}

extern "C" void kernel_launch(void* const* d_in, const int* in_sizes, int n_in,
                              void* d_out, int out_size, void* d_ws, size_t ws_size,
                              hipStream_t stream) {
    const float* positions = (const float*)d_in[0];
    float* out = (float*)d_out;

    // 3072 virtual rows x 6144 pairs, 2 pairs/thread -> 12 blocks of 256 per row.
    dim3 grid(N_ATOMS / 512, N_ATOMS / 2);
    nbr_pairs_kernel<<<grid, 256, 0, stream>>>(positions, out);
}